// Round 6
// baseline (438.692 us; speedup 1.0000x reference)
//
#include <hip/hip_runtime.h>

// ---------------------------------------------------------------------------
// FastRCNN head: RoIPool + FC(25088->4096) + FC(4096->4096) + heads (21/84).
// R6 = R5 + (1) A-fragment register prefetch 1 iter deep (kills per-iter
// exposed global latency — the dominant term per R5 counters), and
// (2) B staging remapped to thread->(k-quad, single column) with ds_write_b64
// (write banks now keyed by per-lane column bits -> ~2-way instead of 8-way).
// LDS data layout and read side identical to R5 (validated).
// ---------------------------------------------------------------------------

typedef __attribute__((ext_vector_type(8))) __bf16 bf16x8;
typedef __attribute__((ext_vector_type(4))) float f32x4;

#define N_ROIS 512
#define FH 50
#define FW 50
#define KK1 25088      // 512*49
#define D1 4096

#define BM 512
#define BN 64
#define BK 32

// ---------------------------------------------------------------------------
// RoIPool: block = (roi, channel-group of 64). 4096 blocks (validated R5).
// ---------------------------------------------------------------------------
__global__ __launch_bounds__(256) void roipool_kernel(
    const float* __restrict__ x, const float* __restrict__ rois,
    __bf16* __restrict__ pooled) {
  const int bid = blockIdx.x;
  const int roi = bid >> 3;
  const int cg = bid & 7;
  const float s = 0.0625f;
  const float r0 = rois[roi * 4 + 0], r1 = rois[roi * 4 + 1];
  const float r2 = rois[roi * 4 + 2], r3 = rois[roi * 4 + 3];
  int x1 = (int)(r0 * s); x1 = min(max(x1, 0), FW - 1);
  int y1 = (int)(r1 * s); y1 = min(max(y1, 0), FH - 1);
  int x2 = (int)(r2 * s); x2 = min(max(x2, 0), FW - 1);
  int y2 = (int)(r3 * s); y2 = min(max(y2, 0), FH - 1);
  const int ww = x2 - x1 + 1, hh = y2 - y1 + 1;
  __shared__ int cs[7], ce[7], rs[7], re[7];
  if (threadIdx.x < 7) {
    int i = threadIdx.x;
    cs[i] = x1 + (i * ww) / 7;
    ce[i] = x1 + ((i + 1) * ww + 6) / 7;
    rs[i] = y1 + (i * hh) / 7;
    re[i] = y1 + ((i + 1) * hh + 6) / 7;
  }
  __syncthreads();
  for (int idx = threadIdx.x; idx < 64 * 49; idx += 256) {
    int cl = idx / 49;
    int p = idx - cl * 49;
    int py = p / 7, px = p - py * 7;
    const int c = cg * 64 + cl;
    const float* base = x + (size_t)c * (FH * FW);
    float m = -3.402823466e38f;
    for (int y = rs[py]; y < re[py]; ++y) {
      const float* rowp = base + y * FW;
      for (int xx = cs[px]; xx < ce[px]; ++xx) m = fmaxf(m, rowp[xx]);
    }
    pooled[(size_t)roi * KK1 + c * 49 + p] = (__bf16)m;
  }
}

// ---------------------------------------------------------------------------
// GEMM: part[z][512][npad] = A[512,K](bf16) @ B[K,N](fp32 -> bf16 at stage)
// z = bid & ((1<<zshift)-1) (XCD-pins K-windows), n0 = (bid>>zshift)*64.
// A: 4 x global_load_dwordx4 to registers, PREFETCHED 1 iter ahead (ping-pong).
// B: reg-staged 2-deep. Thread -> (k-quad kq=tid>>6, column c=tid&63):
//    4 coalesced row loads, pack 2 u32, one ds_write_b64 at
//    idx = c*16 + ((kq>>1) ^ ((c>>2)&3))*4 + 2*(kq&1)   [same layout as R5]
// Read (unchanged, R5-validated): b128 at byte c*64 + (ks^((c>>2)&3))*16.
// Sync: lgkmcnt(0) + raw s_barrier per iter; no vmcnt(0) drain anywhere.
// ---------------------------------------------------------------------------
template <typename OutT>
__global__ __launch_bounds__(512, 4) void gemm_kernel(
    const __bf16* __restrict__ A, const float* __restrict__ B,
    OutT* __restrict__ part, int N, int K, int kslice, int npad, int zshift) {
  __shared__ unsigned int Bu[2][1024];  // 2 x 4KB
  const int tid = threadIdx.x;
  const int lane = tid & 63;
  const int w = tid >> 6;
  const int bid = blockIdx.x;
  const int z = bid & ((1 << zshift) - 1);
  const int n0 = (bid >> zshift) * BN;
  const int kbeg = z * kslice;
  const int niters = kslice / BK;  // always even here
  const bool fullN = (n0 + BN) <= N;

  const int fr = lane & 15;
  const int ks = lane >> 4;

  f32x4 acc[4][4];
#pragma unroll
  for (int i = 0; i < 4; ++i)
#pragma unroll
    for (int j = 0; j < 4; ++j) acc[i][j] = (f32x4){0.f, 0.f, 0.f, 0.f};

  // A: lane reads row w*64 + mf*16 + fr, 16B at k = kbeg + it*32 + ks*8
  const __bf16* Arow = A + (size_t)(w * 64 + fr) * K + kbeg + ks * 8;
  const int kmax = kbeg + kslice;

  // B staging: thread -> k-quad + single column
  const int bc = tid & 63;        // column 0..63
  const int bkq = tid >> 6;       // k-quad 0..7, covers k = 4*bkq..4*bkq+3
  const int bidx = bc * 16 + (((bkq >> 1) ^ ((bc >> 2) & 3)) << 2) +
                   2 * (bkq & 1);  // even -> b64-aligned

  // ping-pong register state (static names, rule #20)
  bf16x8 afA0, afA1, afA2, afA3, afB0, afB1, afB2, afB3;
  float bA0, bA1, bA2, bA3, bB0, bB1, bB2, bB3;

#define LOAD_A(d0, d1, d2, d3, t)                              \
  {                                                            \
    int kk = kbeg + (t) * BK;                                  \
    if (kk >= kmax) kk = kbeg; /* clamped dup, never used */   \
    const __bf16* ap = A + (size_t)(w * 64 + fr) * K + kk + ks * 8; \
    d0 = *(const bf16x8*)(ap);                                 \
    d1 = *(const bf16x8*)(ap + (size_t)16 * K);                \
    d2 = *(const bf16x8*)(ap + (size_t)32 * K);                \
    d3 = *(const bf16x8*)(ap + (size_t)48 * K);                \
  }

#define LOAD_B(d0, d1, d2, d3, t)                              \
  {                                                            \
    int kg = kbeg + (t) * BK;                                  \
    if (kg >= kmax) kg = kbeg; /* clamped dup, never used */   \
    const float* g0 = B + (size_t)(kg + 4 * bkq) * N;          \
    if (fullN) {                                               \
      const int cc = n0 + bc;                                  \
      d0 = g0[cc];                                             \
      d1 = g0[(size_t)N + cc];                                 \
      d2 = g0[(size_t)2 * N + cc];                             \
      d3 = g0[(size_t)3 * N + cc];                             \
    } else {                                                   \
      const int cc = n0 + bc;                                  \
      const bool ok = cc < N;                                  \
      d0 = ok ? g0[cc] : 0.f;                                  \
      d1 = ok ? g0[(size_t)N + cc] : 0.f;                      \
      d2 = ok ? g0[(size_t)2 * N + cc] : 0.f;                  \
      d3 = ok ? g0[(size_t)3 * N + cc] : 0.f;                  \
    }                                                          \
  }

#define WRITE_B(buf, s0, s1, s2, s3)                           \
  {                                                            \
    union { __bf16 h[2]; unsigned int u; } p0, p1;             \
    p0.h[0] = (__bf16)s0; p0.h[1] = (__bf16)s1;                \
    p1.h[0] = (__bf16)s2; p1.h[1] = (__bf16)s3;                \
    *(unsigned long long*)&Bu[buf][bidx] =                     \
        ((unsigned long long)p1.u << 32) | p0.u;               \
  }

  // prologue: A(0) in regs; B tiles 0,1 in flight; tile 0 written
  LOAD_A(afA0, afA1, afA2, afA3, 0);
  LOAD_B(bA0, bA1, bA2, bA3, 0);
  LOAD_B(bB0, bB1, bB2, bB3, 1);
  WRITE_B(0, bA0, bA1, bA2, bA3);

#define BODY(it, pA0, pA1, pA2, pA3, nA0, nA1, nA2, nA3,            \
             cB0, cB1, cB2, cB3, oB0, oB1, oB2, oB3)                \
  {                                                                 \
    LOAD_A(nA0, nA1, nA2, nA3, (it) + 1);                           \
    LOAD_B(cB0, cB1, cB2, cB3, (it) + 2);                           \
    asm volatile("s_waitcnt lgkmcnt(0)" ::: "memory");              \
    __builtin_amdgcn_s_barrier();                                   \
    __builtin_amdgcn_sched_barrier(0);                              \
    if ((it) + 1 < niters) WRITE_B(((it) + 1) & 1, oB0, oB1, oB2, oB3); \
    _Pragma("unroll")                                               \
    for (int nf = 0; nf < 4; ++nf) {                                \
      const int c = nf * 16 + fr;                                   \
      const int slot = ks ^ ((c >> 2) & 3);                         \
      bf16x8 bfr = *(const bf16x8*)((const char*)&Bu[(it) & 1][0] + \
                                    c * 64 + slot * 16);            \
      acc[0][nf] = __builtin_amdgcn_mfma_f32_16x16x32_bf16(pA0, bfr, acc[0][nf], 0, 0, 0); \
      acc[1][nf] = __builtin_amdgcn_mfma_f32_16x16x32_bf16(pA1, bfr, acc[1][nf], 0, 0, 0); \
      acc[2][nf] = __builtin_amdgcn_mfma_f32_16x16x32_bf16(pA2, bfr, acc[2][nf], 0, 0, 0); \
      acc[3][nf] = __builtin_amdgcn_mfma_f32_16x16x32_bf16(pA3, bfr, acc[3][nf], 0, 0, 0); \
    }                                                               \
  }

  for (int it = 0; it < niters; it += 2) {
    // even iter: consume afA / Bu[0]-parity, prefetch into afB; B: load->bA, write<-bB
    BODY(it, afA0, afA1, afA2, afA3, afB0, afB1, afB2, afB3,
         bA0, bA1, bA2, bA3, bB0, bB1, bB2, bB3);
    // odd iter: consume afB, prefetch into afA; B: load->bB, write<-bA
    BODY(it + 1, afB0, afB1, afB2, afB3, afA0, afA1, afA2, afA3,
         bB0, bB1, bB2, bB3, bA0, bA1, bA2, bA3);
  }
#undef BODY
#undef WRITE_B
#undef LOAD_B
#undef LOAD_A

  // epilogue: C/D layout col = lane&15, row = (lane>>4)*4 + r
  const int r0 = ks * 4;
  OutT* pbase = part + (size_t)z * 512 * npad;
#pragma unroll
  for (int mf = 0; mf < 4; ++mf)
#pragma unroll
    for (int nf = 0; nf < 4; ++nf) {
      const int col = n0 + nf * 16 + fr;
#pragma unroll
      for (int r = 0; r < 4; ++r) {
        const int row = w * 64 + mf * 16 + r0 + r;
        pbase[(size_t)row * npad + col] = (OutT)acc[mf][nf][r];
      }
    }
}

// sum bf16 split-K partials + bias, relu -> bf16 activations [512][4096]
__global__ __launch_bounds__(256) void reduce_relu_kernel(
    const __bf16* __restrict__ part, const float* __restrict__ bias,
    __bf16* __restrict__ out, int nsplit) {
  const int idx = blockIdx.x * 256 + threadIdx.x;
  const int flat = idx * 8;
  if (flat >= 512 * 4096) return;
  float s[8];
#pragma unroll
  for (int j = 0; j < 8; ++j) s[j] = 0.f;
  for (int sp = 0; sp < nsplit; ++sp) {
    bf16x8 v = *(const bf16x8*)(part + (size_t)sp * (512 * 4096) + flat);
#pragma unroll
    for (int j = 0; j < 8; ++j) s[j] += (float)v[j];
  }
  const int nb = flat & 4095;
  bf16x8 o;
#pragma unroll
  for (int j = 0; j < 8; ++j) {
    float v = s[j] + bias[nb + j];
    o[j] = (__bf16)(v > 0.f ? v : 0.f);
  }
  *(bf16x8*)(out + flat) = o;
}

// final: sum split-K fp32 partials + bias -> d_out fp32 (cls then reg)
__global__ __launch_bounds__(256) void reduce_out_kernel(
    const float* __restrict__ pc, const float* __restrict__ pr,
    const float* __restrict__ bcls, const float* __restrict__ breg,
    float* __restrict__ out, int nsplit) {
  const int gid = blockIdx.x * 256 + threadIdx.x;
  if (gid >= 512 * 105) return;
  if (gid < 512 * 21) {
    const int m = gid / 21, j = gid - m * 21;
    float s = bcls[j];
    for (int sp = 0; sp < nsplit; ++sp)
      s += pc[(size_t)sp * 512 * 64 + m * 64 + j];
    out[gid] = s;
  } else {
    const int g = gid - 512 * 21;
    const int m = g / 84, j = g - m * 84;
    float s = breg[j];
    for (int sp = 0; sp < nsplit; ++sp)
      s += pr[(size_t)sp * 512 * 128 + m * 128 + j];
    out[gid] = s;
  }
}

extern "C" void kernel_launch(void* const* d_in, const int* in_sizes, int n_in,
                              void* d_out, int out_size, void* d_ws, size_t ws_size,
                              hipStream_t stream) {
  (void)in_sizes; (void)n_in; (void)out_size;
  const float* x    = (const float*)d_in[0];
  const float* rois = (const float*)d_in[2];
  const float* W1   = (const float*)d_in[3];
  const float* b1   = (const float*)d_in[4];
  const float* W2   = (const float*)d_in[5];
  const float* b2   = (const float*)d_in[6];
  const float* Wcls = (const float*)d_in[7];
  const float* bcls = (const float*)d_in[8];
  const float* Wreg = (const float*)d_in[9];
  const float* breg = (const float*)d_in[10];
  float* out = (float*)d_out;

  const size_t pooled_b = (size_t)512 * KK1 * 2;        // 25,690,112
  const size_t act_b = (size_t)512 * D1 * 2;            // 4 MiB
  const size_t need8 = pooled_b + (size_t)8 * act_b + 2 * act_b;
  const int ns = (ws_size >= need8) ? 8 : 2;            // ns=8 confirmed runs
  const int zshift = (ns == 8) ? 3 : 1;

  char* ws = (char*)d_ws;
  __bf16* pooled = (__bf16*)ws;
  __bf16* part1 = (__bf16*)(ws + pooled_b);             // ns * 4MiB
  __bf16* f1 = (__bf16*)(ws + pooled_b + (size_t)ns * act_b);
  __bf16* f2 = (__bf16*)(ws + pooled_b + (size_t)ns * act_b + act_b);
  __bf16* part2 = (__bf16*)ws;                          // alias dead pooled+part1
  float* pcls = (float*)ws;                             // heads phase aliases
  float* preg = (float*)(ws + (size_t)64 * 512 * 64 * 4);  // +8.4MB

  // 1) RoIPool -> pooled bf16 [512, 25088]; 4096 blocks for occupancy
  roipool_kernel<<<N_ROIS * 8, 256, 0, stream>>>(x, rois, pooled);

  // 2) GEMM1: pooled @ W1[25088,4096]; W1 read exactly once; z-pinned XCDs
  gemm_kernel<__bf16><<<64 * ns, 512, 0, stream>>>(
      pooled, W1, part1, 4096, KK1, KK1 / ns, 4096, zshift);
  reduce_relu_kernel<<<1024, 256, 0, stream>>>(part1, b1, f1, ns);

  // 3) GEMM2: f1 @ W2[4096,4096]
  gemm_kernel<__bf16><<<64 * ns, 512, 0, stream>>>(
      f1, W2, part2, 4096, 4096, 4096 / ns, 4096, zshift);
  reduce_relu_kernel<<<1024, 256, 0, stream>>>(part2, b2, f2, ns);

  // 4) heads: split-K=64 (zshift 6): grids 64 / 128 blocks
  gemm_kernel<float><<<1 * 64, 512, 0, stream>>>(
      f2, Wcls, pcls, 21, 4096, 64, 64, 6);
  gemm_kernel<float><<<2 * 64, 512, 0, stream>>>(
      f2, Wreg, preg, 84, 4096, 64, 128, 6);
  reduce_out_kernel<<<(512 * 105 + 255) / 256, 256, 0, stream>>>(
      pcls, preg, bcls, breg, out, 64);
}

// Round 7
// 358.723 us; speedup vs baseline: 1.2229x; 1.2229x over previous
//
#include <hip/hip_runtime.h>

// ---------------------------------------------------------------------------
// FastRCNN head: RoIPool + FC(25088->4096) + FC(4096->4096) + heads (21/84).
// R7: BN 64->128 (wave tile 64x128, acc[4][8]). Rationale: R4/R5/R6 all pin at
// ~3500cy/block-iter regardless of conflicts/prefetch; per-CU A-reads from L2
// were 64KB/iter-slot = ~22 TB/s aggregate = L2 BW wall. BN=128 halves A L2
// traffic per output. 1 block/CU (VGPR ~200), grid 256 = 32 ntiles x 8 z.
// B: thread->(k-octet, col), 8 coalesced loads, pack, ONE ds_write_b128.
// ---------------------------------------------------------------------------

typedef __attribute__((ext_vector_type(8))) __bf16 bf16x8;
typedef __attribute__((ext_vector_type(4))) float f32x4;
typedef __attribute__((ext_vector_type(4))) unsigned int u32x4;

#define N_ROIS 512
#define FH 50
#define FW 50
#define KK1 25088      // 512*49
#define D1 4096

#define BM 512
#define BN 128
#define BK 32

// ---------------------------------------------------------------------------
// RoIPool: block = (roi, channel-group of 64). 4096 blocks (validated R5/R6).
// ---------------------------------------------------------------------------
__global__ __launch_bounds__(256) void roipool_kernel(
    const float* __restrict__ x, const float* __restrict__ rois,
    __bf16* __restrict__ pooled) {
  const int bid = blockIdx.x;
  const int roi = bid >> 3;
  const int cg = bid & 7;
  const float s = 0.0625f;
  const float r0 = rois[roi * 4 + 0], r1 = rois[roi * 4 + 1];
  const float r2 = rois[roi * 4 + 2], r3 = rois[roi * 4 + 3];
  int x1 = (int)(r0 * s); x1 = min(max(x1, 0), FW - 1);
  int y1 = (int)(r1 * s); y1 = min(max(y1, 0), FH - 1);
  int x2 = (int)(r2 * s); x2 = min(max(x2, 0), FW - 1);
  int y2 = (int)(r3 * s); y2 = min(max(y2, 0), FH - 1);
  const int ww = x2 - x1 + 1, hh = y2 - y1 + 1;
  __shared__ int cs[7], ce[7], rs[7], re[7];
  if (threadIdx.x < 7) {
    int i = threadIdx.x;
    cs[i] = x1 + (i * ww) / 7;
    ce[i] = x1 + ((i + 1) * ww + 6) / 7;
    rs[i] = y1 + (i * hh) / 7;
    re[i] = y1 + ((i + 1) * hh + 6) / 7;
  }
  __syncthreads();
  for (int idx = threadIdx.x; idx < 64 * 49; idx += 256) {
    int cl = idx / 49;
    int p = idx - cl * 49;
    int py = p / 7, px = p - py * 7;
    const int c = cg * 64 + cl;
    const float* base = x + (size_t)c * (FH * FW);
    float m = -3.402823466e38f;
    for (int y = rs[py]; y < re[py]; ++y) {
      const float* rowp = base + y * FW;
      for (int xx = cs[px]; xx < ce[px]; ++xx) m = fmaxf(m, rowp[xx]);
    }
    pooled[(size_t)roi * KK1 + c * 49 + p] = (__bf16)m;
  }
}

// ---------------------------------------------------------------------------
// GEMM: part[z][512][npad] = A[512,K](bf16) @ B[K,N](fp32 -> bf16 at stage)
// z = bid & ((1<<zshift)-1) (XCD-pins K-windows), n0 = (bid>>zshift)*128.
// Wave tile 64 rows x 128 cols; acc[4][8]; A prefetched 1 iter (ping-pong).
// B tile 32x128: thread -> (k-octet kq=tid>>7, col c=tid&127); 8 coalesced
// scalar loads; pack 4 u32 (bf16 k-pairs); one ds_write_b128 at u32 idx
// c*16 + (kq ^ ((c>>2)&3))*4. Read (R5-validated formula): b128 at
// c*64 + (ks^((c>>2)&3))*16 for nf = 0..7.
// Sync: lgkmcnt(0) + raw s_barrier per iter; no vmcnt(0) drain anywhere.
// ---------------------------------------------------------------------------
template <typename OutT>
__global__ __launch_bounds__(512, 2) void gemm_kernel(
    const __bf16* __restrict__ A, const float* __restrict__ B,
    OutT* __restrict__ part, int N, int K, int kslice, int npad, int zshift) {
  __shared__ unsigned int Bu[2][2048];  // 2 x 8KB
  const int tid = threadIdx.x;
  const int lane = tid & 63;
  const int w = tid >> 6;
  const int bid = blockIdx.x;
  const int z = bid & ((1 << zshift) - 1);
  const int n0 = (bid >> zshift) * BN;
  const int kbeg = z * kslice;
  const int niters = kslice / BK;  // even in all our calls
  const bool fullN = (n0 + BN) <= N;

  const int fr = lane & 15;
  const int ks = lane >> 4;

  f32x4 acc[4][8];
#pragma unroll
  for (int i = 0; i < 4; ++i)
#pragma unroll
    for (int j = 0; j < 8; ++j) acc[i][j] = (f32x4){0.f, 0.f, 0.f, 0.f};

  const int kmax = kbeg + kslice;

  // B staging: thread -> k-octet + single column
  const int bc = tid & 127;       // column 0..127
  const int bkq = tid >> 7;       // k-octet 0..3, rows 8*bkq..8*bkq+7
  const int bidx = bc * 16 + ((bkq ^ ((bc >> 2) & 3)) << 2);  // 16B aligned

  // ping-pong register state (static names, rule #20)
  bf16x8 afA0, afA1, afA2, afA3, afB0, afB1, afB2, afB3;
  float bA0, bA1, bA2, bA3, bA4, bA5, bA6, bA7;
  float bB0, bB1, bB2, bB3, bB4, bB5, bB6, bB7;

#define LOAD_A(d0, d1, d2, d3, t)                                   \
  {                                                                 \
    int kk = kbeg + (t) * BK;                                       \
    if (kk >= kmax) kk = kbeg; /* clamped dup, never consumed */    \
    const __bf16* ap = A + (size_t)(w * 64 + fr) * K + kk + ks * 8; \
    d0 = *(const bf16x8*)(ap);                                      \
    d1 = *(const bf16x8*)(ap + (size_t)16 * K);                     \
    d2 = *(const bf16x8*)(ap + (size_t)32 * K);                     \
    d3 = *(const bf16x8*)(ap + (size_t)48 * K);                     \
  }

#define LOAD_B(d0, d1, d2, d3, d4, d5, d6, d7, t)              \
  {                                                            \
    int kg = kbeg + (t) * BK;                                  \
    if (kg >= kmax) kg = kbeg; /* clamped dup */               \
    const float* g0 = B + (size_t)(kg + 8 * bkq) * N;          \
    const int cc = n0 + bc;                                    \
    if (fullN) {                                               \
      d0 = g0[cc];                d1 = g0[(size_t)N + cc];     \
      d2 = g0[(size_t)2 * N + cc]; d3 = g0[(size_t)3 * N + cc];\
      d4 = g0[(size_t)4 * N + cc]; d5 = g0[(size_t)5 * N + cc];\
      d6 = g0[(size_t)6 * N + cc]; d7 = g0[(size_t)7 * N + cc];\
    } else {                                                   \
      const bool ok = cc < N;                                  \
      d0 = ok ? g0[cc] : 0.f;                                  \
      d1 = ok ? g0[(size_t)N + cc] : 0.f;                      \
      d2 = ok ? g0[(size_t)2 * N + cc] : 0.f;                  \
      d3 = ok ? g0[(size_t)3 * N + cc] : 0.f;                  \
      d4 = ok ? g0[(size_t)4 * N + cc] : 0.f;                  \
      d5 = ok ? g0[(size_t)5 * N + cc] : 0.f;                  \
      d6 = ok ? g0[(size_t)6 * N + cc] : 0.f;                  \
      d7 = ok ? g0[(size_t)7 * N + cc] : 0.f;                  \
    }                                                          \
  }

#define WRITE_B(buf, s0, s1, s2, s3, s4, s5, s6, s7)           \
  {                                                            \
    union { __bf16 h[2]; unsigned int u; } q0, q1, q2, q3;     \
    q0.h[0] = (__bf16)s0; q0.h[1] = (__bf16)s1;                \
    q1.h[0] = (__bf16)s2; q1.h[1] = (__bf16)s3;                \
    q2.h[0] = (__bf16)s4; q2.h[1] = (__bf16)s5;                \
    q3.h[0] = (__bf16)s6; q3.h[1] = (__bf16)s7;                \
    *(u32x4*)&Bu[buf][bidx] = (u32x4){q0.u, q1.u, q2.u, q3.u}; \
  }

  // prologue: A(0) in regs; B tiles 0,1 in flight; tile 0 written
  LOAD_A(afA0, afA1, afA2, afA3, 0);
  LOAD_B(bA0, bA1, bA2, bA3, bA4, bA5, bA6, bA7, 0);
  LOAD_B(bB0, bB1, bB2, bB3, bB4, bB5, bB6, bB7, 1);
  WRITE_B(0, bA0, bA1, bA2, bA3, bA4, bA5, bA6, bA7);

#define BODY(it, pA0, pA1, pA2, pA3, nA0, nA1, nA2, nA3, cB, oB)      \
  {                                                                   \
    LOAD_A(nA0, nA1, nA2, nA3, (it) + 1);                             \
    LOAD_B(cB##0, cB##1, cB##2, cB##3, cB##4, cB##5, cB##6, cB##7,    \
           (it) + 2);                                                 \
    asm volatile("s_waitcnt lgkmcnt(0)" ::: "memory");                \
    __builtin_amdgcn_s_barrier();                                     \
    __builtin_amdgcn_sched_barrier(0);                                \
    if ((it) + 1 < niters)                                            \
      WRITE_B(((it) + 1) & 1, oB##0, oB##1, oB##2, oB##3, oB##4,      \
              oB##5, oB##6, oB##7);                                   \
    _Pragma("unroll")                                                 \
    for (int nf = 0; nf < 8; ++nf) {                                  \
      const int c = nf * 16 + fr;                                     \
      const int slot = ks ^ ((c >> 2) & 3);                           \
      bf16x8 bfr = *(const bf16x8*)((const char*)&Bu[(it) & 1][0] +   \
                                    c * 64 + slot * 16);              \
      acc[0][nf] = __builtin_amdgcn_mfma_f32_16x16x32_bf16(pA0, bfr, acc[0][nf], 0, 0, 0); \
      acc[1][nf] = __builtin_amdgcn_mfma_f32_16x16x32_bf16(pA1, bfr, acc[1][nf], 0, 0, 0); \
      acc[2][nf] = __builtin_amdgcn_mfma_f32_16x16x32_bf16(pA2, bfr, acc[2][nf], 0, 0, 0); \
      acc[3][nf] = __builtin_amdgcn_mfma_f32_16x16x32_bf16(pA3, bfr, acc[3][nf], 0, 0, 0); \
    }                                                                 \
  }

  for (int it = 0; it < niters; it += 2) {
    BODY(it, afA0, afA1, afA2, afA3, afB0, afB1, afB2, afB3, bA, bB);
    BODY(it + 1, afB0, afB1, afB2, afB3, afA0, afA1, afA2, afA3, bB, bA);
  }
#undef BODY
#undef WRITE_B
#undef LOAD_B
#undef LOAD_A

  // epilogue: C/D layout col = lane&15, row = (lane>>4)*4 + r
  const int r0 = ks * 4;
  OutT* pbase = part + (size_t)z * 512 * npad;
#pragma unroll
  for (int mf = 0; mf < 4; ++mf)
#pragma unroll
    for (int nf = 0; nf < 8; ++nf) {
      const int col = n0 + nf * 16 + fr;
#pragma unroll
      for (int r = 0; r < 4; ++r) {
        const int row = w * 64 + mf * 16 + r0 + r;
        pbase[(size_t)row * npad + col] = (OutT)acc[mf][nf][r];
      }
    }
}

// sum bf16 split-K partials + bias, relu -> bf16 activations [512][4096]
__global__ __launch_bounds__(256) void reduce_relu_kernel(
    const __bf16* __restrict__ part, const float* __restrict__ bias,
    __bf16* __restrict__ out, int nsplit) {
  const int idx = blockIdx.x * 256 + threadIdx.x;
  const int flat = idx * 8;
  if (flat >= 512 * 4096) return;
  float s[8];
#pragma unroll
  for (int j = 0; j < 8; ++j) s[j] = 0.f;
  for (int sp = 0; sp < nsplit; ++sp) {
    bf16x8 v = *(const bf16x8*)(part + (size_t)sp * (512 * 4096) + flat);
#pragma unroll
    for (int j = 0; j < 8; ++j) s[j] += (float)v[j];
  }
  const int nb = flat & 4095;
  bf16x8 o;
#pragma unroll
  for (int j = 0; j < 8; ++j) {
    float v = s[j] + bias[nb + j];
    o[j] = (__bf16)(v > 0.f ? v : 0.f);
  }
  *(bf16x8*)(out + flat) = o;
}

// final: sum split-K fp32 partials (stride 128) + bias -> d_out fp32
__global__ __launch_bounds__(256) void reduce_out_kernel(
    const float* __restrict__ pc, const float* __restrict__ pr,
    const float* __restrict__ bcls, const float* __restrict__ breg,
    float* __restrict__ out, int nsplit) {
  const int gid = blockIdx.x * 256 + threadIdx.x;
  if (gid >= 512 * 105) return;
  if (gid < 512 * 21) {
    const int m = gid / 21, j = gid - m * 21;
    float s = bcls[j];
    for (int sp = 0; sp < nsplit; ++sp)
      s += pc[(size_t)sp * 512 * 128 + m * 128 + j];
    out[gid] = s;
  } else {
    const int g = gid - 512 * 21;
    const int m = g / 84, j = g - m * 84;
    float s = breg[j];
    for (int sp = 0; sp < nsplit; ++sp)
      s += pr[(size_t)sp * 512 * 128 + m * 128 + j];
    out[gid] = s;
  }
}

extern "C" void kernel_launch(void* const* d_in, const int* in_sizes, int n_in,
                              void* d_out, int out_size, void* d_ws, size_t ws_size,
                              hipStream_t stream) {
  (void)in_sizes; (void)n_in; (void)out_size;
  const float* x    = (const float*)d_in[0];
  const float* rois = (const float*)d_in[2];
  const float* W1   = (const float*)d_in[3];
  const float* b1   = (const float*)d_in[4];
  const float* W2   = (const float*)d_in[5];
  const float* b2   = (const float*)d_in[6];
  const float* Wcls = (const float*)d_in[7];
  const float* bcls = (const float*)d_in[8];
  const float* Wreg = (const float*)d_in[9];
  const float* breg = (const float*)d_in[10];
  float* out = (float*)d_out;

  const size_t pooled_b = (size_t)512 * KK1 * 2;        // 25,690,112
  const size_t act_b = (size_t)512 * D1 * 2;            // 4 MiB
  const size_t need8 = pooled_b + (size_t)8 * act_b + 2 * act_b;
  const int ns = (ws_size >= need8) ? 8 : 2;            // ns=8 confirmed runs
  const int zshift = (ns == 8) ? 3 : 1;

  char* ws = (char*)d_ws;
  __bf16* pooled = (__bf16*)ws;
  __bf16* part1 = (__bf16*)(ws + pooled_b);             // ns * 4MiB
  __bf16* f1 = (__bf16*)(ws + pooled_b + (size_t)ns * act_b);
  __bf16* f2 = (__bf16*)(ws + pooled_b + (size_t)ns * act_b + act_b);
  __bf16* part2 = (__bf16*)ws;                          // alias dead pooled+part1
  float* pcls = (float*)ws;                             // heads phase aliases
  float* preg = (float*)(ws + (size_t)64 * 512 * 128 * 4);  // +16.8MB

  // 1) RoIPool -> pooled bf16 [512, 25088]; 4096 blocks for occupancy
  roipool_kernel<<<N_ROIS * 8, 256, 0, stream>>>(x, rois, pooled);

  // 2) GEMM1: pooled @ W1[25088,4096]; W1 read exactly once; z-pinned XCDs
  gemm_kernel<__bf16><<<32 * ns, 512, 0, stream>>>(
      pooled, W1, part1, 4096, KK1, KK1 / ns, 4096, zshift);
  reduce_relu_kernel<<<1024, 256, 0, stream>>>(part1, b1, f1, ns);

  // 3) GEMM2: f1 @ W2[4096,4096]
  gemm_kernel<__bf16><<<32 * ns, 512, 0, stream>>>(
      f1, W2, part2, 4096, 4096, 4096 / ns, 4096, zshift);
  reduce_relu_kernel<<<1024, 256, 0, stream>>>(part2, b2, f2, ns);

  // 4) heads: single n-tile each (21,84 <= 128), split-K=64, npad=128
  gemm_kernel<float><<<64, 512, 0, stream>>>(
      f2, Wcls, pcls, 21, 4096, 64, 128, 6);
  gemm_kernel<float><<<64, 512, 0, stream>>>(
      f2, Wreg, preg, 84, 4096, 64, 128, 6);
  reduce_out_kernel<<<(512 * 105 + 255) / 256, 256, 0, stream>>>(
      pcls, preg, bcls, breg, out, 64);
}